// Round 9
// baseline (268.184 us; speedup 1.0000x reference)
//
#include <hip/hip_runtime.h>

// ---------------------------------------------------------------------------
// LinearSelfAttention: B=4 T=4096 DIM=1024 H=16 E=64 BUCKET=64 U=64
// ---------------------------------------------------------------------------

#define T_LEN 4096
#define DIMN  1024
#define NHEAD 16
#define NB    4
#define MROWS (NB * T_LEN)   // 16384

typedef float f32x4 __attribute__((ext_vector_type(4)));
typedef short s16x8 __attribute__((ext_vector_type(8)));
typedef short s16x4 __attribute__((ext_vector_type(4)));
using u16 = unsigned short;

__device__ __forceinline__ u16 f2bf(float f) {
  unsigned int u = __float_as_uint(f);
  u += 0x7fffu + ((u >> 16) & 1u);   // RNE
  return (u16)(u >> 16);
}
__device__ __forceinline__ float bf2f(u16 h) {
  return __uint_as_float(((unsigned int)h) << 16);
}
// involution swizzle within a slot ([rows][32 bf16] = row*64B)
__device__ __forceinline__ int swz16k(int off) {
  return off ^ (((off >> 7) & 3) << 4);
}

// ------------------- fused weight transpose+cast AND x cast ----------------
__global__ __launch_bounds__(256) void cvt_all_kern(const float* __restrict__ x,
                                                    const float* __restrict__ W0,
                                                    const float* __restrict__ W1,
                                                    const float* __restrict__ W2,
                                                    const float* __restrict__ W3,
                                                    u16* __restrict__ WT,
                                                    u16* __restrict__ xb) {
  __shared__ float tile[64][65];
  const int tid = threadIdx.x;
  if (blockIdx.x < 1024) {
    const int blk = blockIdx.x & 255;
    const int sel = blockIdx.x >> 8;
    const float* W = (sel == 0) ? W0 : (sel == 1) ? W1 : (sel == 2) ? W2 : W3;
    u16* dst = WT + (size_t)sel * DIMN * DIMN;
    const int k0 = (blk >> 4) << 6;
    const int n0 = (blk & 15) << 6;
    const int r = tid >> 6;
    const int c = tid & 63;
#pragma unroll
    for (int i = 0; i < 16; ++i) {
      int row = (i << 2) + r;
      tile[row][c] = W[(size_t)(k0 + row) * DIMN + n0 + c];
    }
    __syncthreads();
#pragma unroll
    for (int i = 0; i < 16; ++i) {
      int row = (i << 2) + r;
      dst[(size_t)(n0 + row) * DIMN + k0 + c] = f2bf(tile[c][row]);
    }
  } else {
    size_t i = ((size_t)(blockIdx.x - 1024) * 256 + tid) * 4;
    f32x4 v = *(const f32x4*)(x + i);
    s16x4 o;
    o.x = (short)f2bf(v.x); o.y = (short)f2bf(v.y);
    o.z = (short)f2bf(v.z); o.w = (short)f2bf(v.w);
    *(s16x4*)(xb + i) = o;
  }
}

// ------------- 128x256 triple-buffered counted-vmcnt bf16 GEMM --------------
// C[M][N] = A[M][1024] * Bt[N][1024]^T.
// MODE 0: N=3072 fused QKV -> q (softmax64), k (elu+1), v  (all bf16)
// MODE 1: N=1024 -> f32 out + bias (direct stores)
// 512 threads = 8 waves (2Mx4N); per-wave 64x64 -> acc[4][4]; BK=32.
// LDS 72KB static: 3 buf x [A 128x32 (8K) | B 256x32 (16K)] -> 2 blocks/CU
// (160/72) with __launch_bounds__(512,4) (VGPR<=128).
// T4 counted-vmcnt, depth 2: per step issue STAGE(t+2) (3 loads), read
// frags(t), MFMA, then vmcnt(3) -- drains tile t+1's loads issued one full
// step earlier (HBM latency off the critical path); NEVER vmcnt(0) in-loop.
// Ledger: outstanding 3 -> +3 = 6 -> drain to 3.  WAR: buf(t+2)%3 overwrote
// tile t-1, whose ds_reads retired before the end-of-(t-1) barrier.
template <int MODE>
__global__ __launch_bounds__(512, 4) void gemm_t(
    const u16* __restrict__ A, const u16* __restrict__ Bt,
    u16* __restrict__ dq, u16* __restrict__ dk, u16* __restrict__ dv,
    float* __restrict__ dO, const float* __restrict__ bias) {
  constexpr int K = 1024;
  constexpr int BNT = (MODE == 0) ? 12 : 4;   // N / 256
  constexpr int NT = K / 32;                  // 32 K-steps
  __shared__ char lds[73728];                 // 3 x 24576

  const int tid = threadIdx.x;
  const int l = tid & 63;
  const int w = tid >> 6;
  const int wm = w >> 2;           // 0..1 (64 rows each)
  const int wn = w & 3;            // 0..3 (64 cols each)

  // per-XCD chunked mapping: 16 bm-rows/XCD in 4 groups of 4, bn-major inside
  const int xcd = (int)blockIdx.x & 7;
  const int idx = (int)blockIdx.x >> 3;
  const int g = idx / (4 * BNT);
  const int r2 = idx % (4 * BNT);
  const int bn = r2 >> 2;
  const int bm = xcd * 16 + g * 4 + (r2 & 3);
  const size_t arow0 = (size_t)bm * 128;
  const size_t brow0 = (size_t)bn * 256;

  int lrow[2], lcol[2];
#pragma unroll
  for (int i = 0; i < 2; ++i) {
    int lg = swz16k(tid * 16 + i * 8192);
    lrow[i] = lg >> 6;
    lcol[i] = (lg & 63) >> 1;
  }

  const int fr = l & 15;
  const int kswz = (((l >> 4) << 4)) ^ ((((fr >> 1) & 3)) << 4);

  auto STAGE = [&](int buf, int matsel, int tt) {  // matsel 0=A (1 issue) 1=B (2)
    const int kbase = (tt & (NT - 1)) * 32;        // wrap tail (harmless)
#pragma unroll
    for (int i = 0; i < 2; ++i) {
      if (matsel == 0 && i == 1) break;
      const u16* src = (matsel == 0)
          ? A  + (arow0 + (size_t)lrow[i]) * K + kbase + lcol[i]
          : Bt + (brow0 + (size_t)lrow[i]) * K + kbase + lcol[i];
      char* dst = lds + (buf * 24576 + matsel * 8192 + i * 8192 + tid * 16);
      __builtin_amdgcn_global_load_lds(
          (__attribute__((address_space(1))) const void*)src,
          (__attribute__((address_space(3))) void*)dst, 16, 0, 0);
    }
  };
  auto LDA = [&](int buf, int rowb) -> s16x8 {
    return *(const s16x8*)(lds + buf * 24576 + rowb * 64 + kswz);
  };
  auto LDB = [&](int buf, int rowb) -> s16x8 {
    return *(const s16x8*)(lds + buf * 24576 + 8192 + rowb * 64 + kswz);
  };

  f32x4 acc[4][4];
#pragma unroll
  for (int i = 0; i < 4; ++i)
#pragma unroll
    for (int j = 0; j < 4; ++j) acc[i][j] = {0.f, 0.f, 0.f, 0.f};

  // prologue: stage tiles 0,1 into buf 0,1 (6 loads); drain tile0 only.
  STAGE(0, 0, 0); STAGE(0, 1, 0);
  STAGE(1, 0, 1); STAGE(1, 1, 1);
  asm volatile("s_waitcnt vmcnt(3)" ::: "memory");
  __builtin_amdgcn_sched_barrier(0);
  __builtin_amdgcn_s_barrier();

  const int amb = wm * 64;
  const int bnb = wn * 64;
  s16x8 af[4], bf[4];

  int bufR = 0, bufW = 2;
#pragma unroll 1
  for (int t = 0; t < NT; ++t) {
    STAGE(bufW, 0, t + 2);
    STAGE(bufW, 1, t + 2);
#pragma unroll
    for (int i = 0; i < 4; ++i) af[i] = LDA(bufR, amb + i * 16 + fr);
#pragma unroll
    for (int i = 0; i < 4; ++i) bf[i] = LDB(bufR, bnb + i * 16 + fr);
    __builtin_amdgcn_s_setprio(1);
#pragma unroll
    for (int mi = 0; mi < 4; ++mi)
#pragma unroll
      for (int ni = 0; ni < 4; ++ni)
        acc[mi][ni] = __builtin_amdgcn_mfma_f32_16x16x32_bf16(
            af[mi], bf[ni], acc[mi][ni], 0, 0, 0);
    __builtin_amdgcn_s_setprio(0);
    asm volatile("s_waitcnt vmcnt(3)" ::: "memory");   // drains tile t+1 (issued last iter)
    __builtin_amdgcn_sched_barrier(0);
    __builtin_amdgcn_s_barrier();
    bufR = (bufR == 2) ? 0 : bufR + 1;
    bufW = (bufW == 2) ? 0 : bufW + 1;
  }

  // ---------------- epilogue: C row = (lane>>4)*4+j, col = lane&15 ----------
  const int r0 = (l >> 4) << 2;
  const int c0 = l & 15;
  if constexpr (MODE == 0) {
    const int mat = bn >> 2;                        // 0=q 1=k 2=v
    u16* dst = (mat == 0) ? dq : ((mat == 1) ? dk : dv);
    const size_t colbase = (size_t)(bn & 3) * 256 + (size_t)wn * 64;
    if (mat == 0) {
      // fused per-head softmax over the wave's 64 cols (= one head)
#pragma unroll
      for (int mi = 0; mi < 4; ++mi) {
#pragma unroll
        for (int j = 0; j < 4; ++j) {
          float v0 = acc[mi][0][j], v1 = acc[mi][1][j];
          float v2 = acc[mi][2][j], v3 = acc[mi][3][j];
          float m = fmaxf(fmaxf(v0, v1), fmaxf(v2, v3));
#pragma unroll
          for (int off = 1; off < 16; off <<= 1) m = fmaxf(m, __shfl_xor(m, off));
          float e0 = __expf(v0 - m), e1 = __expf(v1 - m);
          float e2 = __expf(v2 - m), e3 = __expf(v3 - m);
          float s = e0 + e1 + e2 + e3;
#pragma unroll
          for (int off = 1; off < 16; off <<= 1) s += __shfl_xor(s, off);
          float inv = 1.f / s;
          const size_t row = arow0 + wm * 64 + mi * 16 + r0 + j;
          u16* p = dst + row * DIMN + colbase + c0;
          p[0]  = f2bf(e0 * inv); p[16] = f2bf(e1 * inv);
          p[32] = f2bf(e2 * inv); p[48] = f2bf(e3 * inv);
        }
      }
    } else {
#pragma unroll
      for (int mi = 0; mi < 4; ++mi)
#pragma unroll
        for (int ni = 0; ni < 4; ++ni)
#pragma unroll
          for (int j = 0; j < 4; ++j) {
            const size_t row = arow0 + wm * 64 + mi * 16 + r0 + j;
            float v = acc[mi][ni][j];
            float r = (mat == 1) ? (v > 0.f ? v + 1.f : __expf(v)) : v;
            dst[row * DIMN + colbase + ni * 16 + c0] = f2bf(r);
          }
    }
  } else {
#pragma unroll
    for (int mi = 0; mi < 4; ++mi)
#pragma unroll
      for (int ni = 0; ni < 4; ++ni) {
        const size_t col = brow0 + (size_t)wn * 64 + ni * 16 + c0;
        const float bv = bias[col];
#pragma unroll
        for (int j = 0; j < 4; ++j) {
          const size_t row = arow0 + wm * 64 + mi * 16 + r0 + j;
          dO[row * DIMN + col] = acc[mi][ni][j] + bv;
        }
      }
  }
}

// --------------------------- per-bucket context: C_u = k_u^T v_u ------------
// ctx out is bf16 (f32 accumulation internally); ksum stays f32.
__global__ __launch_bounds__(256) void ctx_bucket_kern(const u16* __restrict__ kb,
                                                       const u16* __restrict__ vb,
                                                       u16* __restrict__ ctx,
                                                       float* __restrict__ ksum) {
  __shared__ float kl[4096];
  __shared__ float vl[4096];
  const int blk = blockIdx.x;
  const int u = blk & 63;
  const int bh = blk >> 6;
  const int b = bh >> 4, h = bh & 15;
  const size_t rowbase = (size_t)b * T_LEN + (size_t)u * 64;
  const int tid = threadIdx.x;
#pragma unroll
  for (int i = 0; i < 16; ++i) {
    int idx = i * 256 + tid;
    int n = idx >> 6, d = idx & 63;
    size_t g = (rowbase + n) * DIMN + (size_t)h * 64 + d;
    kl[idx] = bf2f(kb[g]);
    vl[idx] = bf2f(vb[g]);
  }
  __syncthreads();
  const int dq = (tid & 15) << 2;
  const int eq = (tid >> 4) << 2;
  float a[4][4] = {};
  float ks[4] = {};
  for (int n = 0; n < 64; ++n) {
    f32x4 kv = *(const f32x4*)&kl[n * 64 + dq];
    f32x4 vv = *(const f32x4*)&vl[n * 64 + eq];
#pragma unroll
    for (int i = 0; i < 4; ++i) {
      ks[i] += kv[i];
#pragma unroll
      for (int j = 0; j < 4; ++j) a[i][j] += kv[i] * vv[j];
    }
  }
  const size_t cbase = (size_t)blk * 4096;
#pragma unroll
  for (int i = 0; i < 4; ++i) {
    s16x4 o;
    o.x = (short)f2bf(a[i][0]); o.y = (short)f2bf(a[i][1]);
    o.z = (short)f2bf(a[i][2]); o.w = (short)f2bf(a[i][3]);
    *(s16x4*)&ctx[cbase + (size_t)(dq + i) * 64 + eq] = o;
  }
  if ((tid >> 4) == 0) {
    f32x4 o = {ks[0], ks[1], ks[2], ks[3]};
    *(f32x4*)&ksum[(size_t)blk * 64 + dq] = o;
  }
}

// ---------------- cumsum over u + normalize + shift, in place (bf16) --------
__global__ __launch_bounds__(256) void ctx_cumnorm_kern(u16* __restrict__ ctx,
                                                        const float* __restrict__ ksum) {
  const int tid = blockIdx.x * 256 + threadIdx.x;
  const int bh = tid >> 10;
  const int rem = tid & 1023;
  const int d = rem >> 4;
  const int e0 = (rem & 15) << 2;
  float c0 = 0.f, c1 = 0.f, c2 = 0.f, c3 = 0.f, accK = 0.f;
  for (int u = 0; u < 64; ++u) {
    const size_t base = ((size_t)(bh * 64 + u)) * 4096 + (size_t)d * 64 + e0;
    s16x4 cv4 = *(const s16x4*)&ctx[base];
    float kk = ksum[(size_t)(bh * 64 + u) * 64 + d];
    float x0 = bf2f((u16)cv4.x), x1 = bf2f((u16)cv4.y);
    float x2 = bf2f((u16)cv4.z), x3 = bf2f((u16)cv4.w);
    s16x4 o;
    if (u == 0) {
      o.x = 0; o.y = 0; o.z = 0; o.w = 0;
    } else {
      float inv = 1.f / (accK + 1e-6f);
      o.x = (short)f2bf(c0 * inv); o.y = (short)f2bf(c1 * inv);
      o.z = (short)f2bf(c2 * inv); o.w = (short)f2bf(c3 * inv);
    }
    *(s16x4*)&ctx[base] = o;                       // bucket u sees <= u-1
    c0 += x0; c1 += x1; c2 += x2; c3 += x3;
    accK += kk;
  }
}

// --------------------------- per-bucket attn: q_u @ ctx_u -------------------
__global__ __launch_bounds__(256) void attn_bucket_kern(const u16* __restrict__ qb,
                                                        const u16* __restrict__ ctx,
                                                        u16* __restrict__ attn) {
  __shared__ float qT[64 * 68];
  __shared__ float cl[4096];
  const int blk = blockIdx.x;
  const int u = blk & 63;
  const int bh = blk >> 6;
  const int b = bh >> 4, h = bh & 15;
  const size_t rowbase = (size_t)b * T_LEN + (size_t)u * 64;
  const int tid = threadIdx.x;
  const size_t cbase = (size_t)blk * 4096;
#pragma unroll
  for (int i = 0; i < 16; ++i) {
    int idx = i * 256 + tid;
    int n = idx >> 6, d = idx & 63;
    qT[d * 68 + n] = bf2f(qb[(rowbase + n) * DIMN + (size_t)h * 64 + d]);
  }
#pragma unroll
  for (int i = 0; i < 4; ++i) {
    int idx4 = (i * 256 + tid) * 4;
    s16x4 cv = *(const s16x4*)&ctx[cbase + idx4];
    cl[idx4]     = bf2f((u16)cv.x);
    cl[idx4 + 1] = bf2f((u16)cv.y);
    cl[idx4 + 2] = bf2f((u16)cv.z);
    cl[idx4 + 3] = bf2f((u16)cv.w);
  }
  __syncthreads();
  const int nq = (tid & 15) << 2;
  const int eq = (tid >> 4) << 2;
  float a[4][4] = {};
  for (int d = 0; d < 64; ++d) {
    f32x4 qv = *(const f32x4*)&qT[d * 68 + nq];
    f32x4 cv = *(const f32x4*)&cl[d * 64 + eq];
#pragma unroll
    for (int i = 0; i < 4; ++i)
#pragma unroll
      for (int j = 0; j < 4; ++j) a[i][j] += qv[i] * cv[j];
  }
#pragma unroll
  for (int i = 0; i < 4; ++i) {
    s16x4 o;
    o.x = (short)f2bf(a[i][0]); o.y = (short)f2bf(a[i][1]);
    o.z = (short)f2bf(a[i][2]); o.w = (short)f2bf(a[i][3]);
    *(s16x4*)&attn[(rowbase + nq + i) * DIMN + (size_t)h * 64 + eq] = o;
  }
}

// ---------------------------------------------------------------------------
extern "C" void kernel_launch(void* const* d_in, const int* in_sizes, int n_in,
                              void* d_out, int out_size, void* d_ws, size_t ws_size,
                              hipStream_t stream) {
  const float* x  = (const float*)d_in[0];
  const float* Wq = (const float*)d_in[1];
  const float* Wk = (const float*)d_in[2];
  const float* Wv = (const float*)d_in[3];
  const float* Wo = (const float*)d_in[4];
  const float* bo = (const float*)d_in[5];
  float* out = (float*)d_out;

  constexpr size_t SZ_XB = (size_t)MROWS * DIMN * 2;
  constexpr size_t SZ_WT = (size_t)DIMN * DIMN * 2;
  constexpr size_t SZ_CTX = (size_t)NB * NHEAD * 64 * 64 * 64 * 2;  // bf16
  char* ws = (char*)d_ws;
  u16*   xb   = (u16*)(ws);
  u16*   wqT  = (u16*)(ws + SZ_XB);          // wq/wk/wv/wo contiguous
  u16*   woT  = (u16*)(ws + SZ_XB + 3 * SZ_WT);
  u16*   qb   = (u16*)(ws + SZ_XB + 4 * SZ_WT);
  u16*   kb   = (u16*)(ws + 2 * SZ_XB + 4 * SZ_WT);
  u16*   vb   = (u16*)(ws + 3 * SZ_XB + 4 * SZ_WT);
  u16*   ctx  = (u16*)(ws + 4 * SZ_XB + 4 * SZ_WT);
  float* ksum = (float*)(ws + 4 * SZ_XB + 4 * SZ_WT + SZ_CTX);
  u16*   attn = xb;  // xb dead after QKV GEMM

  cvt_all_kern<<<1024 + MROWS * DIMN / 1024, 256, 0, stream>>>(x, Wq, Wk, Wv, Wo,
                                                               wqT, xb);

  // fused QKV: N = 3072, grid 128 x 12 = 1536
  gemm_t<0><<<1536, 512, 0, stream>>>(xb, wqT, qb, kb, vb, nullptr, nullptr);

  ctx_bucket_kern<<<NB * NHEAD * 64, 256, 0, stream>>>(kb, vb, ctx, ksum);
  ctx_cumnorm_kern<<<256, 256, 0, stream>>>(ctx, ksum);
  attn_bucket_kern<<<NB * NHEAD * 64, 256, 0, stream>>>(qb, ctx, attn);

  // output: N = 1024, grid 128 x 4 = 512
  gemm_t<1><<<512, 512, 0, stream>>>(attn, woT, nullptr, nullptr, nullptr, out, bo);
}

// Round 10
// 247.003 us; speedup vs baseline: 1.0858x; 1.0858x over previous
//
#include <hip/hip_runtime.h>

// ---------------------------------------------------------------------------
// LinearSelfAttention: B=4 T=4096 DIM=1024 H=16 E=64 BUCKET=64 U=64
// ---------------------------------------------------------------------------

#define T_LEN 4096
#define DIMN  1024
#define NHEAD 16
#define NB    4
#define MROWS (NB * T_LEN)   // 16384

typedef float f32x4 __attribute__((ext_vector_type(4)));
typedef short s16x8 __attribute__((ext_vector_type(8)));
typedef short s16x4 __attribute__((ext_vector_type(4)));
using u16 = unsigned short;

__device__ __forceinline__ u16 f2bf(float f) {
  unsigned int u = __float_as_uint(f);
  u += 0x7fffu + ((u >> 16) & 1u);   // RNE
  return (u16)(u >> 16);
}
__device__ __forceinline__ float bf2f(u16 h) {
  return __uint_as_float(((unsigned int)h) << 16);
}
// involution swizzle within a slot ([rows][32 bf16] = row*64B)
__device__ __forceinline__ int swz16k(int off) {
  return off ^ (((off >> 7) & 3) << 4);
}

// ------------------- fused weight transpose+cast AND x cast ----------------
__global__ __launch_bounds__(256) void cvt_all_kern(const float* __restrict__ x,
                                                    const float* __restrict__ W0,
                                                    const float* __restrict__ W1,
                                                    const float* __restrict__ W2,
                                                    const float* __restrict__ W3,
                                                    u16* __restrict__ WT,
                                                    u16* __restrict__ xb) {
  __shared__ float tile[64][65];
  const int tid = threadIdx.x;
  if (blockIdx.x < 1024) {
    const int blk = blockIdx.x & 255;
    const int sel = blockIdx.x >> 8;
    const float* W = (sel == 0) ? W0 : (sel == 1) ? W1 : (sel == 2) ? W2 : W3;
    u16* dst = WT + (size_t)sel * DIMN * DIMN;
    const int k0 = (blk >> 4) << 6;
    const int n0 = (blk & 15) << 6;
    const int r = tid >> 6;
    const int c = tid & 63;
#pragma unroll
    for (int i = 0; i < 16; ++i) {
      int row = (i << 2) + r;
      tile[row][c] = W[(size_t)(k0 + row) * DIMN + n0 + c];
    }
    __syncthreads();
#pragma unroll
    for (int i = 0; i < 16; ++i) {
      int row = (i << 2) + r;
      dst[(size_t)(n0 + row) * DIMN + k0 + c] = f2bf(tile[c][row]);
    }
  } else {
    size_t i = ((size_t)(blockIdx.x - 1024) * 256 + tid) * 4;
    f32x4 v = *(const f32x4*)(x + i);
    s16x4 o;
    o.x = (short)f2bf(v.x); o.y = (short)f2bf(v.y);
    o.z = (short)f2bf(v.z); o.w = (short)f2bf(v.w);
    *(s16x4*)(xb + i) = o;
  }
}

// ------------- 128x256 triple-buffered counted-vmcnt bf16 GEMM --------------
// MODE 0: N=3072 fused QKV -> q (softmax64, [n][dim]), k (elu+1 -> kT[bh][d][t]),
//         v (-> vT[bh][d][t])     (all bf16)
// MODE 1: N=1024 -> f32 out + bias (direct stores)
// R9 core unchanged: 8 waves 2Mx4N, BK=32, 3 LDS buffers, vmcnt(3) counted.
template <int MODE>
__global__ __launch_bounds__(512, 4) void gemm_t(
    const u16* __restrict__ A, const u16* __restrict__ Bt,
    u16* __restrict__ dq, u16* __restrict__ dk, u16* __restrict__ dv,
    float* __restrict__ dO, const float* __restrict__ bias) {
  constexpr int K = 1024;
  constexpr int BNT = (MODE == 0) ? 12 : 4;   // N / 256
  constexpr int NT = K / 32;                  // 32 K-steps
  __shared__ char lds[73728];                 // 3 x 24576

  const int tid = threadIdx.x;
  const int l = tid & 63;
  const int w = tid >> 6;
  const int wm = w >> 2;           // 0..1 (64 rows each)
  const int wn = w & 3;            // 0..3 (64 cols each)

  const int xcd = (int)blockIdx.x & 7;
  const int idx = (int)blockIdx.x >> 3;
  const int g = idx / (4 * BNT);
  const int r2 = idx % (4 * BNT);
  const int bn = r2 >> 2;
  const int bm = xcd * 16 + g * 4 + (r2 & 3);
  const size_t arow0 = (size_t)bm * 128;
  const size_t brow0 = (size_t)bn * 256;

  int lrow[2], lcol[2];
#pragma unroll
  for (int i = 0; i < 2; ++i) {
    int lg = swz16k(tid * 16 + i * 8192);
    lrow[i] = lg >> 6;
    lcol[i] = (lg & 63) >> 1;
  }

  const int fr = l & 15;
  const int kswz = (((l >> 4) << 4)) ^ ((((fr >> 1) & 3)) << 4);

  auto STAGE = [&](int buf, int matsel, int tt) {
    const int kbase = (tt & (NT - 1)) * 32;
#pragma unroll
    for (int i = 0; i < 2; ++i) {
      if (matsel == 0 && i == 1) break;
      const u16* src = (matsel == 0)
          ? A  + (arow0 + (size_t)lrow[i]) * K + kbase + lcol[i]
          : Bt + (brow0 + (size_t)lrow[i]) * K + kbase + lcol[i];
      char* dst = lds + (buf * 24576 + matsel * 8192 + i * 8192 + tid * 16);
      __builtin_amdgcn_global_load_lds(
          (__attribute__((address_space(1))) const void*)src,
          (__attribute__((address_space(3))) void*)dst, 16, 0, 0);
    }
  };
  auto LDA = [&](int buf, int rowb) -> s16x8 {
    return *(const s16x8*)(lds + buf * 24576 + rowb * 64 + kswz);
  };
  auto LDB = [&](int buf, int rowb) -> s16x8 {
    return *(const s16x8*)(lds + buf * 24576 + 8192 + rowb * 64 + kswz);
  };

  f32x4 acc[4][4];
#pragma unroll
  for (int i = 0; i < 4; ++i)
#pragma unroll
    for (int j = 0; j < 4; ++j) acc[i][j] = {0.f, 0.f, 0.f, 0.f};

  STAGE(0, 0, 0); STAGE(0, 1, 0);
  STAGE(1, 0, 1); STAGE(1, 1, 1);
  asm volatile("s_waitcnt vmcnt(3)" ::: "memory");
  __builtin_amdgcn_sched_barrier(0);
  __builtin_amdgcn_s_barrier();

  const int amb = wm * 64;
  const int bnb = wn * 64;
  s16x8 af[4], bf[4];

  int bufR = 0, bufW = 2;
#pragma unroll 1
  for (int t = 0; t < NT; ++t) {
    STAGE(bufW, 0, t + 2);
    STAGE(bufW, 1, t + 2);
#pragma unroll
    for (int i = 0; i < 4; ++i) af[i] = LDA(bufR, amb + i * 16 + fr);
#pragma unroll
    for (int i = 0; i < 4; ++i) bf[i] = LDB(bufR, bnb + i * 16 + fr);
    __builtin_amdgcn_s_setprio(1);
#pragma unroll
    for (int mi = 0; mi < 4; ++mi)
#pragma unroll
      for (int ni = 0; ni < 4; ++ni)
        acc[mi][ni] = __builtin_amdgcn_mfma_f32_16x16x32_bf16(
            af[mi], bf[ni], acc[mi][ni], 0, 0, 0);
    __builtin_amdgcn_s_setprio(0);
    asm volatile("s_waitcnt vmcnt(3)" ::: "memory");
    __builtin_amdgcn_sched_barrier(0);
    __builtin_amdgcn_s_barrier();
    bufR = (bufR == 2) ? 0 : bufR + 1;
    bufW = (bufW == 2) ? 0 : bufW + 1;
  }

  // ---------------- epilogue: D row=(l>>4)*4+j, col=l&15 --------------------
  const int r0 = (l >> 4) << 2;
  const int c0 = l & 15;
  if constexpr (MODE == 0) {
    const int mat = bn >> 2;                        // 0=q 1=k 2=v
    if (mat == 0) {
      u16* dst = dq;
      const size_t colbase = (size_t)(bn & 3) * 256 + (size_t)wn * 64;
      // fused per-head softmax over the wave's 64 cols (= one head)
#pragma unroll
      for (int mi = 0; mi < 4; ++mi) {
#pragma unroll
        for (int j = 0; j < 4; ++j) {
          float v0 = acc[mi][0][j], v1 = acc[mi][1][j];
          float v2 = acc[mi][2][j], v3 = acc[mi][3][j];
          float m = fmaxf(fmaxf(v0, v1), fmaxf(v2, v3));
#pragma unroll
          for (int off = 1; off < 16; off <<= 1) m = fmaxf(m, __shfl_xor(m, off));
          float e0 = __expf(v0 - m), e1 = __expf(v1 - m);
          float e2 = __expf(v2 - m), e3 = __expf(v3 - m);
          float s = e0 + e1 + e2 + e3;
#pragma unroll
          for (int off = 1; off < 16; off <<= 1) s += __shfl_xor(s, off);
          float inv = 1.f / s;
          const size_t row = arow0 + wm * 64 + mi * 16 + r0 + j;
          u16* p = dst + row * DIMN + colbase + c0;
          p[0]  = f2bf(e0 * inv); p[16] = f2bf(e1 * inv);
          p[32] = f2bf(e2 * inv); p[48] = f2bf(e3 * inv);
        }
      }
    } else {
      // transposed write -> kT/vT [bh][d][t], s16x4 along t (j = token)
      u16* dst = (mat == 1) ? dk : dv;
      const int colb = (bn & 3) * 256 + wn * 64;    // col within 1024
#pragma unroll
      for (int mi = 0; mi < 4; ++mi) {
        const size_t row = arow0 + wm * 64 + mi * 16 + r0;   // j=0 token row
        const int bb = (int)(row >> 12);
        const int t = (int)(row & 4095);
#pragma unroll
        for (int ni = 0; ni < 4; ++ni) {
          const int col = colb + ni * 16 + c0;
          const int h = col >> 6, d = col & 63;
          s16x4 o;
#pragma unroll
          for (int j = 0; j < 4; ++j) {
            float v = acc[mi][ni][j];
            float r = (mat == 1) ? (v > 0.f ? v + 1.f : __expf(v)) : v;
            o[j] = (short)f2bf(r);
          }
          *(s16x4*)&dst[((size_t)((bb * 16 + h) * 64 + d)) * 4096 + t] = o;
        }
      }
    }
  } else {
#pragma unroll
    for (int mi = 0; mi < 4; ++mi)
#pragma unroll
      for (int ni = 0; ni < 4; ++ni) {
        const size_t col = brow0 + (size_t)wn * 64 + ni * 16 + c0;
        const float bv = bias[col];
#pragma unroll
        for (int j = 0; j < 4; ++j) {
          const size_t row = arow0 + wm * 64 + mi * 16 + r0 + j;
          dO[row * DIMN + col] = acc[mi][ni][j] + bv;
        }
      }
  }
}

// ---------------- per-bucket context via MFMA: ctxT_u[e][d] = v^T k ---------
// wave = one bucket; A = vT rows (m=e), Bt = kT rows (n=d); frags direct from
// global (L2); ksum[d] from the already-loaded B-frags via shuffle reduce.
__global__ __launch_bounds__(256) void ctx_mfma_kern(const u16* __restrict__ kT,
                                                     const u16* __restrict__ vT,
                                                     u16* __restrict__ ctxT,
                                                     float* __restrict__ ksum) {
  const int tid = threadIdx.x;
  const int l = tid & 63;
  const int w = tid >> 6;
  const int bh = (int)blockIdx.x >> 4;
  const int u = (((int)blockIdx.x & 15) << 2) + w;
  const size_t tbase = (size_t)bh * 64 * 4096 + (size_t)u * 64;  // +d*4096+n
  const int fr = l & 15;
  const int kg = (l >> 4) << 3;

  s16x8 a[4][2], b[4][2];
#pragma unroll
  for (int mi = 0; mi < 4; ++mi)
#pragma unroll
    for (int kk = 0; kk < 2; ++kk)
      a[mi][kk] = *(const s16x8*)&vT[tbase + (size_t)(mi * 16 + fr) * 4096 +
                                     kk * 32 + kg];
#pragma unroll
  for (int ni = 0; ni < 4; ++ni)
#pragma unroll
    for (int kk = 0; kk < 2; ++kk)
      b[ni][kk] = *(const s16x8*)&kT[tbase + (size_t)(ni * 16 + fr) * 4096 +
                                     kk * 32 + kg];

  f32x4 acc[4][4];
#pragma unroll
  for (int i = 0; i < 4; ++i)
#pragma unroll
    for (int j = 0; j < 4; ++j) acc[i][j] = {0.f, 0.f, 0.f, 0.f};
#pragma unroll
  for (int mi = 0; mi < 4; ++mi)
#pragma unroll
    for (int ni = 0; ni < 4; ++ni)
#pragma unroll
      for (int kk = 0; kk < 2; ++kk)
        acc[mi][ni] = __builtin_amdgcn_mfma_f32_16x16x32_bf16(
            a[mi][kk], b[ni][kk], acc[mi][ni], 0, 0, 0);

  // ksum[d] = sum over bucket tokens of kT[d][.]
  const size_t kbase = ((size_t)bh * 64 + u) * 64;
#pragma unroll
  for (int ni = 0; ni < 4; ++ni) {
    float s = 0.f;
#pragma unroll
    for (int kk = 0; kk < 2; ++kk)
#pragma unroll
      for (int j = 0; j < 8; ++j) s += bf2f((u16)b[ni][kk][j]);
    s += __shfl_xor(s, 16);
    s += __shfl_xor(s, 32);
    if (l < 16) ksum[kbase + ni * 16 + l] = s;
  }

  // D: row = e = (l>>4)*4+j, col = d = l&15 (within 16-blocks)
  const size_t cbase = kbase * 64;   // (bh*64+u)*4096
  const int r0 = (l >> 4) << 2;
#pragma unroll
  for (int mi = 0; mi < 4; ++mi)
#pragma unroll
    for (int ni = 0; ni < 4; ++ni)
#pragma unroll
      for (int j = 0; j < 4; ++j)
        ctxT[cbase + (size_t)(mi * 16 + r0 + j) * 64 + ni * 16 + fr] =
            f2bf(acc[mi][ni][j]);
}

// ---------- cumsum over u + normalize + shift, in place on ctxT (bf16) ------
// thread owns (bh, e, d-quad); divisor ksum[d] is along the fast dim (f32x4).
__global__ __launch_bounds__(256) void ctx_cumnorm_kern(u16* __restrict__ ctxT,
                                                        const float* __restrict__ ksum) {
  const int tid = blockIdx.x * 256 + threadIdx.x;   // 65536
  const int bh = tid >> 10;
  const int rem = tid & 1023;
  const int e = rem >> 4;
  const int d0 = (rem & 15) << 2;
  f32x4 c = {0.f, 0.f, 0.f, 0.f};
  f32x4 accK = {0.f, 0.f, 0.f, 0.f};
  for (int u = 0; u < 64; ++u) {
    const size_t cb = (((size_t)(bh * 64 + u)) * 64 + e) * 64 + d0;
    s16x4 raw = *(const s16x4*)&ctxT[cb];
    f32x4 kk = *(const f32x4*)&ksum[((size_t)(bh * 64 + u)) * 64 + d0];
    s16x4 o;
    if (u == 0) {
      o.x = 0; o.y = 0; o.z = 0; o.w = 0;
    } else {
      o.x = (short)f2bf(c.x / (accK.x + 1e-6f));
      o.y = (short)f2bf(c.y / (accK.y + 1e-6f));
      o.z = (short)f2bf(c.z / (accK.z + 1e-6f));
      o.w = (short)f2bf(c.w / (accK.w + 1e-6f));
    }
    *(s16x4*)&ctxT[cb] = o;                      // bucket u sees <= u-1
    c.x += bf2f((u16)raw.x); c.y += bf2f((u16)raw.y);
    c.z += bf2f((u16)raw.z); c.w += bf2f((u16)raw.w);
    accK += kk;
  }
}

// ---------------- per-bucket attn via MFMA: attn_u = q_u @ C_u --------------
// wave = one bucket; A = q rows (natural), Bt = ctxT rows (natural).
__global__ __launch_bounds__(256) void attn_mfma_kern(const u16* __restrict__ qb,
                                                      const u16* __restrict__ ctxT,
                                                      u16* __restrict__ attn) {
  const int tid = threadIdx.x;
  const int l = tid & 63;
  const int w = tid >> 6;
  const int bh = (int)blockIdx.x >> 4;
  const int u = (((int)blockIdx.x & 15) << 2) + w;
  const int b = bh >> 4, h = bh & 15;
  const size_t rowbase = (size_t)b * T_LEN + (size_t)u * 64;
  const size_t cbase = ((size_t)bh * 64 + u) * 4096;
  const int fr = l & 15;
  const int kg = (l >> 4) << 3;

  s16x8 a[4][2], bfr[4][2];
#pragma unroll
  for (int mi = 0; mi < 4; ++mi)
#pragma unroll
    for (int kk = 0; kk < 2; ++kk)
      a[mi][kk] = *(const s16x8*)&qb[(rowbase + mi * 16 + fr) * DIMN +
                                     (size_t)h * 64 + kk * 32 + kg];
#pragma unroll
  for (int ni = 0; ni < 4; ++ni)
#pragma unroll
    for (int kk = 0; kk < 2; ++kk)
      bfr[ni][kk] = *(const s16x8*)&ctxT[cbase + (size_t)(ni * 16 + fr) * 64 +
                                         kk * 32 + kg];

  f32x4 acc[4][4];
#pragma unroll
  for (int i = 0; i < 4; ++i)
#pragma unroll
    for (int j = 0; j < 4; ++j) acc[i][j] = {0.f, 0.f, 0.f, 0.f};
#pragma unroll
  for (int mi = 0; mi < 4; ++mi)
#pragma unroll
    for (int ni = 0; ni < 4; ++ni)
#pragma unroll
      for (int kk = 0; kk < 2; ++kk)
        acc[mi][ni] = __builtin_amdgcn_mfma_f32_16x16x32_bf16(
            a[mi][kk], bfr[ni][kk], acc[mi][ni], 0, 0, 0);

  const int r0 = (l >> 4) << 2;
#pragma unroll
  for (int mi = 0; mi < 4; ++mi)
#pragma unroll
    for (int ni = 0; ni < 4; ++ni)
#pragma unroll
      for (int j = 0; j < 4; ++j)
        attn[(rowbase + mi * 16 + r0 + j) * DIMN + (size_t)h * 64 +
             ni * 16 + fr] = f2bf(acc[mi][ni][j]);
}

// ---------------------------------------------------------------------------
extern "C" void kernel_launch(void* const* d_in, const int* in_sizes, int n_in,
                              void* d_out, int out_size, void* d_ws, size_t ws_size,
                              hipStream_t stream) {
  const float* x  = (const float*)d_in[0];
  const float* Wq = (const float*)d_in[1];
  const float* Wk = (const float*)d_in[2];
  const float* Wv = (const float*)d_in[3];
  const float* Wo = (const float*)d_in[4];
  const float* bo = (const float*)d_in[5];
  float* out = (float*)d_out;

  constexpr size_t SZ_XB = (size_t)MROWS * DIMN * 2;
  constexpr size_t SZ_WT = (size_t)DIMN * DIMN * 2;
  constexpr size_t SZ_CTX = (size_t)NB * NHEAD * 64 * 64 * 64 * 2;  // bf16
  char* ws = (char*)d_ws;
  u16*   xb   = (u16*)(ws);
  u16*   wqT  = (u16*)(ws + SZ_XB);          // wq/wk/wv/wo contiguous
  u16*   woT  = (u16*)(ws + SZ_XB + 3 * SZ_WT);
  u16*   qb   = (u16*)(ws + SZ_XB + 4 * SZ_WT);
  u16*   kT   = (u16*)(ws + 2 * SZ_XB + 4 * SZ_WT);   // [bh][d][t]
  u16*   vT   = (u16*)(ws + 3 * SZ_XB + 4 * SZ_WT);   // [bh][d][t]
  u16*   ctxT = (u16*)(ws + 4 * SZ_XB + 4 * SZ_WT);   // [bh][u][e][d]
  float* ksum = (float*)(ws + 4 * SZ_XB + 4 * SZ_WT + SZ_CTX);
  u16*   attn = xb;  // xb dead after QKV GEMM

  cvt_all_kern<<<1024 + MROWS * DIMN / 1024, 256, 0, stream>>>(x, Wq, Wk, Wv, Wo,
                                                               wqT, xb);

  // fused QKV: N = 3072, grid 128 x 12 = 1536
  gemm_t<0><<<1536, 512, 0, stream>>>(xb, wqT, qb, kT, vT, nullptr, nullptr);

  ctx_mfma_kern<<<NB * NHEAD * 16, 256, 0, stream>>>(kT, vT, ctxT, ksum);
  ctx_cumnorm_kern<<<256, 256, 0, stream>>>(ctxT, ksum);
  attn_mfma_kern<<<NB * NHEAD * 16, 256, 0, stream>>>(qb, ctxT, attn);

  // output: N = 1024, grid 128 x 4 = 512
  gemm_t<1><<<512, 512, 0, stream>>>(attn, woT, nullptr, nullptr, nullptr, out, bo);
}